// Round 5
// baseline (623.341 us; speedup 1.0000x reference)
//
#include <hip/hip_runtime.h>

#define N_NODES 100000
#define N_EDGES 3200000
#define F_IN 512
#define HIDDEN 16
#define N_LABELS 64

#define BW 128
#define NBUCK ((N_NODES + BW - 1) / BW)     // 782
#define NCB 256
#define SCAN_N (NBUCK * NCB)                // 200192
#define SCAN_BLKS ((SCAN_N + 1023) / 1024)  // 196
#define CAP 10240                           // LDS staging entries (40KB); buckets are 4096 +/- 64

// r9: count/scatter at 512 threads (was 256): same grid/layout, 2x resident
// waves (1->2 waves/SIMD) to hide HBM+atomic latency.
__global__ __launch_bounds__(512) void count_kernel(
        const int* __restrict__ es, const int* __restrict__ ed,
        int* __restrict__ Msrc, int* __restrict__ Mdst) {
    __shared__ int h1[NBUCK], h2[NBUCK];
    const int tid = threadIdx.x, g = blockIdx.x;
    for (int i = tid; i < NBUCK; i += 512) { h1[i] = 0; h2[i] = 0; }
    __syncthreads();
    for (int i = g * 512 + tid; i < N_EDGES; i += NCB * 512) {
        atomicAdd(&h1[es[i] >> 7], 1);
        atomicAdd(&h2[ed[i] >> 7], 1);
    }
    __syncthreads();
    for (int i = tid; i < NBUCK; i += 512) {
        Msrc[i * NCB + g] = h1[i];
        Mdst[i * NCB + g] = h2[i];
    }
}

// r9: scanA/B/C each handle BOTH arrays via blockIdx.y (6 launches -> 3).
__global__ __launch_bounds__(256) void scanA_kernel(
        int* __restrict__ a0, int* __restrict__ a1,
        int* __restrict__ b0, int* __restrict__ b1) {
    int* a    = blockIdx.y ? a1 : a0;
    int* bsum = blockIdx.y ? b1 : b0;
    __shared__ int s[256];
    const int tid = threadIdx.x;
    const int base = blockIdx.x * 1024 + tid * 4;
    int4 v = make_int4(0, 0, 0, 0);
    if (base + 3 < SCAN_N) v = *(const int4*)(a + base);
    else {
        if (base + 0 < SCAN_N) v.x = a[base + 0];
        if (base + 1 < SCAN_N) v.y = a[base + 1];
        if (base + 2 < SCAN_N) v.z = a[base + 2];
        if (base + 3 < SCAN_N) v.w = a[base + 3];
    }
    const int lsum = v.x + v.y + v.z + v.w;
    s[tid] = lsum;
    __syncthreads();
    for (int off = 1; off < 256; off <<= 1) {
        int t = (tid >= off) ? s[tid - off] : 0;
        __syncthreads();
        s[tid] += t;
        __syncthreads();
    }
    int e0 = s[tid] - lsum;
    int e1 = e0 + v.x, e2 = e1 + v.y, e3 = e2 + v.z;
    if (base + 3 < SCAN_N) *(int4*)(a + base) = make_int4(e0, e1, e2, e3);
    else {
        if (base + 0 < SCAN_N) a[base + 0] = e0;
        if (base + 1 < SCAN_N) a[base + 1] = e1;
        if (base + 2 < SCAN_N) a[base + 2] = e2;
        if (base + 3 < SCAN_N) a[base + 3] = e3;
    }
    if (tid == 255) bsum[blockIdx.x] = s[255];
}

__global__ void scanB_kernel(int* __restrict__ b0, int* __restrict__ b1) {
    int* bsum = blockIdx.y ? b1 : b0;
    __shared__ int s[256];
    const int tid = threadIdx.x;
    int v = (tid < SCAN_BLKS) ? bsum[tid] : 0;
    s[tid] = v;
    __syncthreads();
    for (int off = 1; off < 256; off <<= 1) {
        int t = (tid >= off) ? s[tid - off] : 0;
        __syncthreads();
        s[tid] += t;
        __syncthreads();
    }
    if (tid < SCAN_BLKS) bsum[tid] = s[tid] - v;
}

__global__ __launch_bounds__(256) void scanC_kernel(
        int* __restrict__ a0, int* __restrict__ a1,
        const int* __restrict__ b0, const int* __restrict__ b1) {
    int* a = blockIdx.y ? a1 : a0;
    const int* bsum = blockIdx.y ? b1 : b0;
    const int base = blockIdx.x * 1024 + threadIdx.x * 4;
    const int b = bsum[blockIdx.x];
    if (base + 3 < SCAN_N) {
        int4 v = *(int4*)(a + base);
        v.x += b; v.y += b; v.z += b; v.w += b;
        *(int4*)(a + base) = v;
    } else {
        for (int j = 0; j < 4; ++j) if (base + j < SCAN_N) a[base + j] += b;
    }
}

__global__ __launch_bounds__(512) void scatter_kernel(
        const int* __restrict__ es, const int* __restrict__ ed,
        const int* __restrict__ Ssrc, const int* __restrict__ Sdst,
        unsigned* __restrict__ pairs, unsigned char* __restrict__ srcb) {
    __shared__ int c1[NBUCK], c2[NBUCK];
    const int tid = threadIdx.x, g = blockIdx.x;
    for (int i = tid; i < NBUCK; i += 512) {
        c1[i] = Ssrc[i * NCB + g];
        c2[i] = Sdst[i * NCB + g];
    }
    __syncthreads();
    for (int i = g * 512 + tid; i < N_EDGES; i += NCB * 512) {
        int s = es[i], d = ed[i];
        int p2 = atomicAdd(&c2[d >> 7], 1);
        pairs[p2] = ((unsigned)(d & 127) << 17) | (unsigned)s;
        int p1 = atomicAdd(&c1[s >> 7], 1);
        srcb[p1] = (unsigned char)(s & 127);
    }
}

// Per-dst-bucket fine sort; converts pairs -> col IN PLACE.
__global__ __launch_bounds__(256) void csr_kernel(
        const int* __restrict__ Sdst, unsigned* __restrict__ pairs,
        int* __restrict__ row_ptr, float* __restrict__ norm_dst) {
    __shared__ unsigned buf[CAP];
    __shared__ int hist[BW], scn[BW], cur[BW];
    const int b = blockIdx.x, tid = threadIdx.x;
    const int base  = Sdst[b * NCB];
    const int nextb = (b == NBUCK - 1) ? N_EDGES : Sdst[(b + 1) * NCB];
    const int nb = nextb - base;
    const bool fits = (nb <= CAP);   // always true for this input (+96 sigma)
    if (tid < BW) hist[tid] = 0;
    __syncthreads();
    for (int i = tid; i < nb; i += 256) {
        unsigned pk = pairs[base + i];
        if (fits) buf[i] = pk;
        atomicAdd(&hist[pk >> 17], 1);
    }
    __syncthreads();
    if (tid < BW) scn[tid] = hist[tid];
    __syncthreads();
    for (int off = 1; off < BW; off <<= 1) {
        int t = 0;
        if (tid < BW && tid >= off) t = scn[tid - off];
        __syncthreads();
        if (tid < BW) scn[tid] += t;
        __syncthreads();
    }
    if (tid < BW) {
        int e = scn[tid] - hist[tid];
        cur[tid] = e;
        int node = b * BW + tid;
        if (node <= N_NODES) row_ptr[node] = base + e;
        if (node < N_NODES) norm_dst[node] = rsqrtf(fmaxf((float)hist[tid], 1.0f));
    }
    __syncthreads();
    if (fits) {
        for (int i = tid; i < nb; i += 256) {
            unsigned pk = buf[i];
            int pos = atomicAdd(&cur[pk >> 17], 1);
            pairs[base + pos] = pk & 0x1FFFFu;   // col value, within-bucket perm
        }
    } else {
        for (int i = tid; i < nb; i += 256)
            pairs[base + i] &= 0x1FFFFu;
    }
}

__global__ __launch_bounds__(256) void srcdeg_kernel(
        const int* __restrict__ Ssrc, const unsigned char* __restrict__ srcb,
        float* __restrict__ norm_src) {
    __shared__ int hist[BW];
    const int b = blockIdx.x, tid = threadIdx.x;
    const int base  = Ssrc[b * NCB];
    const int nextb = (b == NBUCK - 1) ? N_EDGES : Ssrc[(b + 1) * NCB];
    const int nb = nextb - base;
    if (tid < BW) hist[tid] = 0;
    __syncthreads();
    for (int i = tid; i < nb; i += 256)
        atomicAdd(&hist[srcb[base + i]], 1);
    __syncthreads();
    if (tid < BW) {
        int node = b * BW + tid;
        if (node < N_NODES) norm_src[node] = rsqrtf(fmaxf((float)hist[tid], 1.0f));
    }
}

// r9 proj1: single pass over all K=512 (KSPLIT gone). X staged via
// gload_lds double-buffer (r8 structure, 2x32KB, swizzled source + swizzled
// read, 2-way-free banks). W1 read straight from global: one 64B line per k,
// L1/L2-resident across all blocks -> no W staging, no extra barrier deps.
// TWO acc banks (k0-255 / k256-511) summed at the end reproduce the old
// (P0+P1)*ns arithmetic BIT-EXACTLY (absmax must stay 0.0009765625).
// reduce1 is deleted; H1 written directly with norm_src folded in.
// 512 thr, 64KB LDS -> 2 blocks/CU = 4 waves/SIMD.
#define P1_ROWS 256
#define P1_CH 32
#define P1_CHUNKS (F_IN / P1_CH)                      // 16
#define P1_BLKS ((N_NODES + P1_ROWS - 1) / P1_ROWS)   // 391

#define GLD16(gp, lp) __builtin_amdgcn_global_load_lds( \
    (const __attribute__((address_space(1))) unsigned int*)(gp), \
    (__attribute__((address_space(3))) unsigned int*)(lp), 16, 0, 0)

__device__ __forceinline__ void p1_stage(const float* __restrict__ X,
                                         int node0, int c, float* lbuf,
                                         int srow0, int scg, int wbase) {
    // 2048 16B-units = 256 rows x 8 col-groups; 512 threads x 4 units.
    // 8 consecutive lanes cover one row's 128B (source cols XOR-permuted,
    // same 128B line set -> fully coalesced); LDS dest linear (rule #21).
#pragma unroll
    for (int it = 0; it < 4; ++it) {
        int row = srow0 + it * 64;
        int grow = node0 + row;
        if (grow > N_NODES - 1) grow = N_NODES - 1;   // clamp; write guarded
        int cg = scg ^ ((row >> 2) & 7);
        const float* gp = X + (size_t)grow * F_IN + (size_t)c * P1_CH + cg * 4;
        float* lp = lbuf + (size_t)(it * 512 + wbase) * 4;
        GLD16(gp, lp);
    }
}

__global__ __launch_bounds__(512, 4) void proj1_kernel(
        const float* __restrict__ X, const float* __restrict__ W1,
        const float* __restrict__ norm_src, float* __restrict__ H1) {
    __shared__ float xs[2][P1_ROWS * P1_CH];   // 2 x 32 KB

    const int tid = threadIdx.x;
    const int node0 = blockIdx.x * P1_ROWS;

    const int srow0 = tid >> 3;        // + it*64
    const int scg   = tid & 7;
    const int wbase = tid & 448;       // wave-uniform base (16B units)

    p1_stage(X, node0, 0, &xs[0][0], srow0, scg, wbase);
    __syncthreads();

    const int rg = tid >> 2;           // 0..127 -> rows rg*2, rg*2+1
    const int kq = (tid & 3) * 4;      // output quad
    const int sw = (rg >> 1) & 7;      // read-side swizzle (== (row>>2)&7)

    float acc0[2][4];
#pragma unroll
    for (int a = 0; a < 2; ++a)
#pragma unroll
        for (int b = 0; b < 4; ++b) acc0[a][b] = 0.f;

#define P1_COMPUTE(ACC, CC) do {                                              \
    const float* xb = &xs[(CC) & 1][0];                                       \
    _Pragma("unroll")                                                         \
    for (int kk4 = 0; kk4 < 8; ++kk4) {                                       \
        const int k = (CC) * P1_CH + kk4 * 4;                                 \
        float4 w0 = *((const float4*)(W1 + (size_t)(k + 0) * HIDDEN + kq));   \
        float4 w1 = *((const float4*)(W1 + (size_t)(k + 1) * HIDDEN + kq));   \
        float4 w2 = *((const float4*)(W1 + (size_t)(k + 2) * HIDDEN + kq));   \
        float4 w3 = *((const float4*)(W1 + (size_t)(k + 3) * HIDDEN + kq));   \
        _Pragma("unroll")                                                     \
        for (int a = 0; a < 2; ++a) {                                         \
            int row = rg * 2 + a;                                             \
            float4 xv = *((const float4*)&xb[row * P1_CH + ((kk4 ^ sw) * 4)]);\
            ACC[a][0] += xv.x * w0.x; ACC[a][1] += xv.x * w0.y;               \
            ACC[a][2] += xv.x * w0.z; ACC[a][3] += xv.x * w0.w;               \
            ACC[a][0] += xv.y * w1.x; ACC[a][1] += xv.y * w1.y;               \
            ACC[a][2] += xv.y * w1.z; ACC[a][3] += xv.y * w1.w;               \
            ACC[a][0] += xv.z * w2.x; ACC[a][1] += xv.z * w2.y;               \
            ACC[a][2] += xv.z * w2.z; ACC[a][3] += xv.z * w2.w;               \
            ACC[a][0] += xv.w * w3.x; ACC[a][1] += xv.w * w3.y;               \
            ACC[a][2] += xv.w * w3.z; ACC[a][3] += xv.w * w3.w;               \
        }                                                                     \
    }                                                                         \
} while (0)

    // ---- chunks 0..7 -> acc0 (== old z=0 / P0, same inner order) ----
    for (int cc = 0; cc < 8; ++cc) {
        p1_stage(X, node0, cc + 1, &xs[(cc & 1) ^ 1][0], srow0, scg, wbase);
        P1_COMPUTE(acc0, cc);
        __syncthreads();   // implicit vmcnt(0): next buf staged; cur reusable
    }

    float acc1[2][4];
#pragma unroll
    for (int a = 0; a < 2; ++a)
#pragma unroll
        for (int b = 0; b < 4; ++b) acc1[a][b] = 0.f;

    // ---- chunks 8..15 -> acc1 (== old z=1 / P1) ----
    for (int cc = 8; cc < P1_CHUNKS; ++cc) {
        if (cc + 1 < P1_CHUNKS)
            p1_stage(X, node0, cc + 1, &xs[(cc & 1) ^ 1][0], srow0, scg, wbase);
        P1_COMPUTE(acc1, cc);
        __syncthreads();
    }

    // epilogue: H1 = (acc0 + acc1) * norm_src  (bit-identical to reduce1)
#pragma unroll
    for (int a = 0; a < 2; ++a) {
        int gn = node0 + rg * 2 + a;
        if (gn < N_NODES) {
            float ns = norm_src[gn];
            *((float4*)(H1 + (size_t)gn * HIDDEN + kq)) =
                make_float4((acc0[a][0] + acc1[a][0]) * ns,
                            (acc0[a][1] + acc1[a][1]) * ns,
                            (acc0[a][2] + acc1[a][2]) * ns,
                            (acc0[a][3] + acc1[a][3]) * ns);
        }
    }
#undef P1_COMPUTE
}

__global__ __launch_bounds__(256) void spmm1_kernel(
        const int* __restrict__ rp, const int* __restrict__ col,
        const float* __restrict__ H1, const float* __restrict__ norm_dst,
        const float* __restrict__ norm_src, const float* __restrict__ b1,
        float* __restrict__ H1b) {
    int tid = threadIdx.x;
    int node = blockIdx.x * 16 + (tid >> 4);
    int k = tid & 15;
    if (node >= N_NODES) return;
    int beg = rp[node], end = rp[node + 1];
    float acc = 0.f;
    int j = beg;
    for (; j + 3 < end; j += 4) {
        int s0 = col[j], s1 = col[j + 1], s2 = col[j + 2], s3 = col[j + 3];
        float v0 = H1[(size_t)s0 * HIDDEN + k];
        float v1 = H1[(size_t)s1 * HIDDEN + k];
        float v2 = H1[(size_t)s2 * HIDDEN + k];
        float v3 = H1[(size_t)s3 * HIDDEN + k];
        acc += v0 + v1 + v2 + v3;
    }
    for (; j < end; ++j) acc += H1[(size_t)col[j] * HIDDEN + k];
    float v = fmaxf(acc * norm_dst[node] + b1[k], 0.f) * norm_src[node];
    H1b[(size_t)node * HIDDEN + k] = v;
}

__global__ __launch_bounds__(256) void spmm2_final_kernel(
        const int* __restrict__ rp, const int* __restrict__ col,
        const float* __restrict__ H1b, const float* __restrict__ norm_dst,
        const float* __restrict__ W2, const float* __restrict__ b2,
        float* __restrict__ out) {
    __shared__ float w2s[HIDDEN * N_LABELS];
    int tid = threadIdx.x;
    ((float4*)w2s)[tid] = ((const float4*)W2)[tid];
    __syncthreads();

    int node = blockIdx.x * 16 + (tid >> 4);
    int k = tid & 15;
    if (node >= N_NODES) return;
    int beg = rp[node], end = rp[node + 1];
    float acc = 0.f;
    int j = beg;
    for (; j + 3 < end; j += 4) {
        int s0 = col[j], s1 = col[j + 1], s2 = col[j + 2], s3 = col[j + 3];
        float v0 = H1b[(size_t)s0 * HIDDEN + k];
        float v1 = H1b[(size_t)s1 * HIDDEN + k];
        float v2 = H1b[(size_t)s2 * HIDDEN + k];
        float v3 = H1b[(size_t)s3 * HIDDEN + k];
        acc += v0 + v1 + v2 + v3;
    }
    for (; j < end; ++j) acc += H1b[(size_t)col[j] * HIDDEN + k];
    acc *= norm_dst[node];

    float4 o = ((const float4*)b2)[k];
#pragma unroll
    for (int jj = 0; jj < HIDDEN; ++jj) {
        float hj = __shfl(acc, jj, 16);
        float4 w = *((const float4*)&w2s[jj * N_LABELS + 4 * k]);
        o.x += hj * w.x; o.y += hj * w.y; o.z += hj * w.z; o.w += hj * w.w;
    }
    ((float4*)out)[(size_t)node * 16 + k] = o;
}

extern "C" void kernel_launch(void* const* d_in, const int* in_sizes, int n_in,
                              void* d_out, int out_size, void* d_ws, size_t ws_size,
                              hipStream_t stream) {
    const float* X  = (const float*)d_in[0];
    const float* W1 = (const float*)d_in[1];
    const float* b1 = (const float*)d_in[2];
    const float* W2 = (const float*)d_in[3];
    const float* b2 = (const float*)d_in[4];
    const int* es   = (const int*)d_in[5];
    const int* ed   = (const int*)d_in[6];
    float* out = (float*)d_out;

    // ws (~26.8MB): norms | row_ptr | R1 | R2 | R3
    //  R1 (6.4M): srcb (scatter..srcdeg) -> H1 (proj1..spmm1)
    //  R2 (6.4M): Sdst/Ssrc/bs (count..srcdeg) -> H1b (spmm1..end)
    //  R3 (12.8M): pairs (scatter..csr, converted IN PLACE) -> col (..end)
    char* ws = (char*)d_ws;
    float* norm_src = (float*)ws;  ws += (size_t)N_NODES * 4;
    float* norm_dst = (float*)ws;  ws += (size_t)N_NODES * 4;
    int*   row_ptr  = (int*)ws;    ws += 400016;
    char*  R1 = ws;                ws += (size_t)N_NODES * HIDDEN * 4;
    char*  R2 = ws;                ws += (size_t)N_NODES * HIDDEN * 4;
    char*  R3 = ws;

    unsigned char* srcb = (unsigned char*)R1;
    float* H1  = (float*)R1;
    int*   Sdst = (int*)R2;
    int*   Ssrc = (int*)(R2 + 800768);
    int*   bs1  = (int*)(R2 + 1601536);
    int*   bs2  = (int*)(R2 + 1602560);
    float* H1b  = (float*)R2;
    unsigned* pairs = (unsigned*)R3;
    int*   col  = (int*)R3;

    count_kernel<<<NCB, 512, 0, stream>>>(es, ed, Ssrc, Sdst);
    scanA_kernel<<<dim3(SCAN_BLKS, 2), 256, 0, stream>>>(Sdst, Ssrc, bs1, bs2);
    scanB_kernel<<<dim3(1, 2), 256, 0, stream>>>(bs1, bs2);
    scanC_kernel<<<dim3(SCAN_BLKS, 2), 256, 0, stream>>>(Sdst, Ssrc, bs1, bs2);
    scatter_kernel<<<NCB, 512, 0, stream>>>(es, ed, Ssrc, Sdst, pairs, srcb);
    csr_kernel<<<NBUCK, 256, 0, stream>>>(Sdst, pairs, row_ptr, norm_dst);
    srcdeg_kernel<<<NBUCK, 256, 0, stream>>>(Ssrc, srcb, norm_src);
    proj1_kernel<<<P1_BLKS, 512, 0, stream>>>(X, W1, norm_src, H1);
    spmm1_kernel<<<(N_NODES + 15) / 16, 256, 0, stream>>>(row_ptr, col, H1, norm_dst, norm_src, b1, H1b);
    spmm2_final_kernel<<<(N_NODES + 15) / 16, 256, 0, stream>>>(row_ptr, col, H1b, norm_dst, W2, b2, out);
}